// Round 8
// baseline (152.961 us; speedup 1.0000x reference)
//
#include <hip/hip_runtime.h>

#define B_    32
#define H_    640
#define W_    368
#define OH    634          // H - 6
#define OW    362          // W - 6
#define CHUNK 10           // output rows per block
#define NCHUNK 64          // 63 full chunks + last (4 rows); 63*10+4 = 634
#define NBLK  (NCHUNK * B_)          // 2048
#define GROUPS 64

// d_ws layout (floats):
//   [0..31]      per-batch max of target (int-bits atomicMax; 0xAA poison is negative,
//                any positive-float bits win, so no pre-zeroing needed)
//   [64..1087]   64 partial-sum slots, stride 16 floats (64 B); zeroed by k_max blk 0
//   [1088]       completion counter (uint, own cacheline); zeroed by k_max blk 0
#define SLOT0 64
#define STRIDE 16
#define ROOTC 1088

typedef float f2 __attribute__((ext_vector_type(2)));
__device__ __forceinline__ f2 ffma2(f2 a, f2 b, f2 c) { return __builtin_elementwise_fma(a, b, c); }

__global__ __launch_bounds__(256) void k_max(const float* __restrict__ tgt,
                                             float* __restrict__ ws) {
    if (blockIdx.x == 0) {                     // zero slots + counter (stream order vs k_ssim)
        for (int i = threadIdx.x; i < GROUPS * STRIDE + STRIDE; i += 256)
            ws[SLOT0 + i] = 0.0f;
    }
    const int b   = blockIdx.x >> 6;           // 64 segments per batch
    const int seg = blockIdx.x & 63;
    const int perseg = (H_ * W_) / 64;         // 3680 floats
    const float4* p = (const float4*)(tgt + (size_t)b * (H_ * W_) + (size_t)seg * perseg);
    const int n4 = perseg / 4;                 // 920
    float m = 0.0f;
    for (int i = threadIdx.x; i < n4; i += 256) {
        float4 v = p[i];
        m = fmaxf(m, fmaxf(fmaxf(v.x, v.y), fmaxf(v.z, v.w)));
    }
    #pragma unroll
    for (int off = 32; off; off >>= 1)
        m = fmaxf(m, __shfl_down(m, off, 64));
    __shared__ float sm[4];
    const int lane = threadIdx.x & 63, wv = threadIdx.x >> 6;
    if (lane == 0) sm[wv] = m;
    __syncthreads();
    if (threadIdx.x == 0) {
        m = fmaxf(fmaxf(sm[0], sm[1]), fmaxf(sm[2], sm[3]));
        atomicMax((int*)ws + b, __float_as_int(m));   // inputs >= 0
    }
}

__device__ __forceinline__ void loadrow(const float* __restrict__ xr,
                                        const float* __restrict__ yr,
                                        f2 xn[4], f2 yn[4]) {
    const f2* xp = (const f2*)xr;   // (r*368 + 2t)*4 is always 8B-aligned
    const f2* yp = (const f2*)yr;
    xn[0] = xp[0]; xn[1] = xp[1]; xn[2] = xp[2]; xn[3] = xp[3];
    yn[0] = yp[0]; yn[1] = yp[1]; yn[2] = yp[2]; yn[3] = yp[3];
}

// Horizontal 7-sums for TWO adjacent windows (cols c..c+6, c+1..c+7), packed
// into f2 lanes {win0, win1} per quantity: h = {x, y, xx, yy, xy}.
__device__ __forceinline__ void hsum2v(const f2 xn[4], const f2 yn[4], f2 h[5]) {
    const float xs[8] = {xn[0].x, xn[0].y, xn[1].x, xn[1].y, xn[2].x, xn[2].y, xn[3].x, xn[3].y};
    const float ys[8] = {yn[0].x, yn[0].y, yn[1].x, yn[1].y, yn[2].x, yn[2].y, yn[3].x, yn[3].y};
    float hx = 0, hy = 0, hxx = 0, hyy = 0, hxy = 0;
    #pragma unroll
    for (int k = 0; k < 7; ++k) {
        const float xv = xs[k], yv = ys[k];
        hx += xv; hy += yv;
        hxx = fmaf(xv, xv, hxx);
        hyy = fmaf(yv, yv, hyy);
        hxy = fmaf(xv, yv, hxy);
    }
    h[0] = f2{hx,  hx - xs[0] + xs[7]};
    h[1] = f2{hy,  hy - ys[0] + ys[7]};
    h[2] = f2{hxx, fmaf(xs[7], xs[7], fmaf(-xs[0], xs[0], hxx))};
    h[3] = f2{hyy, fmaf(ys[7], ys[7], fmaf(-ys[0], ys[0], hyy))};
    h[4] = f2{hxy, fmaf(xs[7], ys[7], fmaf(-xs[0], ys[0], hxy))};
}

// NOTE: no min-waves clamp — __launch_bounds__(192,4) forced VGPR=64 in R6 and
// the ring spilled to scratch (WRITE_SIZE 96 KB -> 120 MB). Let the allocator float.
__global__ __launch_bounds__(192) void k_ssim(const float* __restrict__ X,
                                              const float* __restrict__ Y,
                                              float* __restrict__ ws,
                                              float* __restrict__ out) {
    const int t    = threadIdx.x;              // 0..191
    const int w    = t >> 6;
    const int lane = t & 63;
    const int b    = blockIdx.y;
    const int r0   = blockIdx.x * CHUNK;
    const int outRows = min(CHUNK, OH - r0);   // 10, or 4 for last chunk
    const int c    = 2 * t;                    // base output col
    const bool colOK = (c < OW);               // t <= 180

    const float dr  = ws[b];
    float C1 = 0.01f * dr; C1 *= C1;
    float C2 = 0.03f * dr; C2 *= C2;
    const f2 c1v = f2{C1 * 2401.0f, C1 * 2401.0f};   // scaled-domain constants
    const f2 c2v = f2{C2 * 2401.0f, C2 * 2401.0f};
    const f2 two    = f2{2.0f, 2.0f};
    const f2 k49    = f2{49.0f, 49.0f};
    const f2 covn2v = f2{2.0f * (49.0f / 48.0f), 2.0f * (49.0f / 48.0f)};
    const f2 covnv  = f2{49.0f / 48.0f, 49.0f / 48.0f};

    const float* xb = X + (size_t)b * (H_ * W_) + c;
    const float* yb = Y + (size_t)b * (H_ * W_) + c;

    f2 acc2 = f2{0.0f, 0.0f};

    if (colOK) {
        f2 ring[5][7];                         // [quantity][row slot], lanes = 2 cols
        f2 tot[5] = {f2{0,0}, f2{0,0}, f2{0,0}, f2{0,0}, f2{0,0}};
        f2 h[5];
        f2 xn[4], yn[4];

        #pragma unroll
        for (int p = 0; p < 6; ++p) {          // prime 6 halo rows
            loadrow(xb + (size_t)(r0 + p) * W_, yb + (size_t)(r0 + p) * W_, xn, yn);
            hsum2v(xn, yn, h);
            #pragma unroll
            for (int q = 0; q < 5; ++q) { ring[q][p] = h[q]; tot[q] += h[q]; }
        }
        loadrow(xb + (size_t)(r0 + 6) * W_, yb + (size_t)(r0 + 6) * W_, xn, yn);

        for (int ii = 0; ii < outRows; ii += 7) {
            #pragma unroll
            for (int p = 0; p < 7; ++p) {      // ring slot == p (compile-time)
                const int i = ii + p;
                if (i >= outRows) break;       // block-uniform
                hsum2v(xn, yn, h);             // consume prefetched row r0+i+6
                if (i + 1 < outRows)           // prefetch row r0+i+7 (covered by math below)
                    loadrow(xb + (size_t)(r0 + i + 7) * W_, yb + (size_t)(r0 + i + 7) * W_, xn, yn);

                #pragma unroll
                for (int q = 0; q < 5; ++q) tot[q] += h[q];

                const f2 tx = tot[0], ty = tot[1], txx = tot[2], tyy = tot[3], txy = tot[4];
                const f2 pxy = tx * ty;
                const f2 A1  = ffma2(pxy, two, c1v);
                const f2 s2  = ffma2(tx, tx, ty * ty);
                const f2 B1  = s2 + c1v;
                const f2 mxy = ffma2(k49, txy, -pxy);
                const f2 A2  = ffma2(covn2v, mxy, c2v);
                const f2 vs  = ffma2(k49, txx + tyy, -s2);
                const f2 B2  = ffma2(covnv, vs, c2v);
                const f2 num = A1 * A2;
                const f2 den = B1 * B2;
                f2 r;
                r.x = __builtin_amdgcn_rcpf(den.x);
                r.y = __builtin_amdgcn_rcpf(den.y);
                acc2 = ffma2(num, r, acc2);

                const int sn = (p + 6) % 7;    // retire slot p, insert new in slot sn
                #pragma unroll
                for (int q = 0; q < 5; ++q) { tot[q] -= ring[q][p]; ring[q][sn] = h[q]; }
            }
        }
    }

    float acc = acc2.x + acc2.y;
    #pragma unroll
    for (int off = 32; off; off >>= 1)
        acc += __shfl_down(acc, off, 64);
    __shared__ float sm[3];
    if (lane == 0) sm[w] = acc;
    __syncthreads();
    if (t == 0) {
        const float s = sm[0] + sm[1] + sm[2];
        const int blk = blockIdx.y * NCHUNK + blockIdx.x;
        float* slots = ws + SLOT0;
        atomicAdd(&slots[(blk & (GROUPS - 1)) * STRIDE], s);   // 64 independent lines
        // Drain this wave's outstanding vmem so the slot-add is at the L2 coherence
        // point before the counter-add issues. Wave-local wait — NOT a cache
        // invalidate (no buffer_inv, unlike __threadfence which killed R5).
        __asm__ volatile("" ::: "memory");
        __builtin_amdgcn_s_waitcnt(0);
        __asm__ volatile("" ::: "memory");
        const unsigned done = atomicAdd((unsigned*)(ws + ROOTC), 1u);
        if (done == NBLK - 1) {                // last block finalizes
            float totsum = 0.0f;
            #pragma unroll
            for (int i = 0; i < GROUPS; ++i)
                totsum += atomicAdd(&slots[i * STRIDE], 0.0f);   // L2-coherent reads
            out[0] = 1.0f - totsum * (1.0f / (32.0f * 634.0f * 362.0f));
        }
    }
}

extern "C" void kernel_launch(void* const* d_in, const int* in_sizes, int n_in,
                              void* d_out, int out_size, void* d_ws, size_t ws_size,
                              hipStream_t stream) {
    const float* X = (const float*)d_in[0];   // 'output'
    const float* Y = (const float*)d_in[1];   // 'target'
    float* ws = (float*)d_ws;

    k_max<<<dim3(2048), dim3(256), 0, stream>>>(Y, ws);
    k_ssim<<<dim3(NCHUNK, B_), dim3(192), 0, stream>>>(X, Y, ws, (float*)d_out);
}

// Round 9
// 139.647 us; speedup vs baseline: 1.0953x; 1.0953x over previous
//
#include <hip/hip_runtime.h>

#define B_    32
#define H_    640
#define W_    368
#define OH    634          // H - 6
#define OW    362          // W - 6
#define CHUNK 10           // output rows per block
#define NCHUNK 64          // 63 full chunks + last (4 rows); 63*10+4 = 634
#define NBLK  (NCHUNK * B_)          // 2048
#define GROUPS 64
#define PER_GROUP (NBLK / GROUPS)    // 32

// d_ws layout (floats):
//   [0..31]      per-batch max of target (int-bits atomicMax; 0xAA poison is negative,
//                any positive-float bits win, so no pre-zeroing needed)
//   [64..1087]   64 partial-sum slots, stride 16 floats (64 B); zeroed by k_max blk 0
//   [1088..2111] 64 group counters (uint), stride 16 (separate lines); zeroed by k_max blk 0
//   [2112]       root counter (uint, own line); zeroed by k_max blk 0
#define SLOT0 64
#define CNT0  1088
#define ROOTC 2112
#define STRIDE 16

typedef float f2 __attribute__((ext_vector_type(2)));
__device__ __forceinline__ f2 ffma2(f2 a, f2 b, f2 c) { return __builtin_elementwise_fma(a, b, c); }

__global__ __launch_bounds__(256) void k_max(const float* __restrict__ tgt,
                                             float* __restrict__ ws) {
    if (blockIdx.x == 0) {                     // zero slots + counters (stream order vs k_ssim)
        for (int i = threadIdx.x; i < 2 * GROUPS * STRIDE + STRIDE; i += 256)
            ws[SLOT0 + i] = 0.0f;
    }
    const int b   = blockIdx.x >> 6;           // 64 segments per batch
    const int seg = blockIdx.x & 63;
    const int perseg = (H_ * W_) / 64;         // 3680 floats
    const float4* p = (const float4*)(tgt + (size_t)b * (H_ * W_) + (size_t)seg * perseg);
    const int n4 = perseg / 4;                 // 920
    float m = 0.0f;
    for (int i = threadIdx.x; i < n4; i += 256) {
        float4 v = p[i];
        m = fmaxf(m, fmaxf(fmaxf(v.x, v.y), fmaxf(v.z, v.w)));
    }
    #pragma unroll
    for (int off = 32; off; off >>= 1)
        m = fmaxf(m, __shfl_down(m, off, 64));
    __shared__ float sm[4];
    const int lane = threadIdx.x & 63, wv = threadIdx.x >> 6;
    if (lane == 0) sm[wv] = m;
    __syncthreads();
    if (threadIdx.x == 0) {
        m = fmaxf(fmaxf(sm[0], sm[1]), fmaxf(sm[2], sm[3]));
        atomicMax((int*)ws + b, __float_as_int(m));   // inputs >= 0
    }
}

__device__ __forceinline__ void loadrow(const float* __restrict__ xr,
                                        const float* __restrict__ yr,
                                        f2 xn[4], f2 yn[4]) {
    const f2* xp = (const f2*)xr;   // (r*368 + 2t)*4 is always 8B-aligned
    const f2* yp = (const f2*)yr;
    xn[0] = xp[0]; xn[1] = xp[1]; xn[2] = xp[2]; xn[3] = xp[3];
    yn[0] = yp[0]; yn[1] = yp[1]; yn[2] = yp[2]; yn[3] = yp[3];
}

// Horizontal 7-sums for TWO adjacent windows (cols c..c+6, c+1..c+7), packed
// into f2 lanes {win0, win1} per quantity: h = {x, y, xx, yy, xy}.
__device__ __forceinline__ void hsum2v(const f2 xn[4], const f2 yn[4], f2 h[5]) {
    const float xs[8] = {xn[0].x, xn[0].y, xn[1].x, xn[1].y, xn[2].x, xn[2].y, xn[3].x, xn[3].y};
    const float ys[8] = {yn[0].x, yn[0].y, yn[1].x, yn[1].y, yn[2].x, yn[2].y, yn[3].x, yn[3].y};
    float hx = 0, hy = 0, hxx = 0, hyy = 0, hxy = 0;
    #pragma unroll
    for (int k = 0; k < 7; ++k) {
        const float xv = xs[k], yv = ys[k];
        hx += xv; hy += yv;
        hxx = fmaf(xv, xv, hxx);
        hyy = fmaf(yv, yv, hyy);
        hxy = fmaf(xv, yv, hxy);
    }
    h[0] = f2{hx,  hx - xs[0] + xs[7]};
    h[1] = f2{hy,  hy - ys[0] + ys[7]};
    h[2] = f2{hxx, fmaf(xs[7], xs[7], fmaf(-xs[0], xs[0], hxx))};
    h[3] = f2{hyy, fmaf(ys[7], ys[7], fmaf(-ys[0], ys[0], hyy))};
    h[4] = f2{hxy, fmaf(xs[7], ys[7], fmaf(-xs[0], ys[0], hxy))};
}

// NOTE: no min-waves clamp — __launch_bounds__(192,4) forced VGPR=64 in R6 and
// the ring spilled. The f2 form naturally lands at 64 VGPR spill-free (R8).
__global__ __launch_bounds__(192) void k_ssim(const float* __restrict__ X,
                                              const float* __restrict__ Y,
                                              float* __restrict__ ws,
                                              float* __restrict__ out) {
    const int t    = threadIdx.x;              // 0..191
    const int w    = t >> 6;
    const int lane = t & 63;
    const int b    = blockIdx.y;
    const int r0   = blockIdx.x * CHUNK;
    const int outRows = min(CHUNK, OH - r0);   // 10, or 4 for last chunk
    const int c    = 2 * t;                    // base output col
    const bool colOK = (c < OW);               // t <= 180

    const float dr  = ws[b];
    float C1 = 0.01f * dr; C1 *= C1;
    float C2 = 0.03f * dr; C2 *= C2;
    const f2 c1v = f2{C1 * 2401.0f, C1 * 2401.0f};   // scaled-domain constants
    const f2 c2v = f2{C2 * 2401.0f, C2 * 2401.0f};
    const f2 two    = f2{2.0f, 2.0f};
    const f2 k49    = f2{49.0f, 49.0f};
    const f2 covn2v = f2{2.0f * (49.0f / 48.0f), 2.0f * (49.0f / 48.0f)};
    const f2 covnv  = f2{49.0f / 48.0f, 49.0f / 48.0f};

    const float* xb = X + (size_t)b * (H_ * W_) + c;
    const float* yb = Y + (size_t)b * (H_ * W_) + c;

    f2 acc2 = f2{0.0f, 0.0f};

    if (colOK) {
        f2 ring[5][7];                         // [quantity][row slot], lanes = 2 cols
        f2 tot[5] = {f2{0,0}, f2{0,0}, f2{0,0}, f2{0,0}, f2{0,0}};
        f2 h[5];
        f2 xn[4], yn[4];

        #pragma unroll
        for (int p = 0; p < 6; ++p) {          // prime 6 halo rows
            loadrow(xb + (size_t)(r0 + p) * W_, yb + (size_t)(r0 + p) * W_, xn, yn);
            hsum2v(xn, yn, h);
            #pragma unroll
            for (int q = 0; q < 5; ++q) { ring[q][p] = h[q]; tot[q] += h[q]; }
        }
        loadrow(xb + (size_t)(r0 + 6) * W_, yb + (size_t)(r0 + 6) * W_, xn, yn);

        for (int ii = 0; ii < outRows; ii += 7) {
            #pragma unroll
            for (int p = 0; p < 7; ++p) {      // ring slot == p (compile-time)
                const int i = ii + p;
                if (i >= outRows) break;       // block-uniform
                hsum2v(xn, yn, h);             // consume prefetched row r0+i+6
                if (i + 1 < outRows)           // prefetch row r0+i+7 (covered by math below)
                    loadrow(xb + (size_t)(r0 + i + 7) * W_, yb + (size_t)(r0 + i + 7) * W_, xn, yn);

                #pragma unroll
                for (int q = 0; q < 5; ++q) tot[q] += h[q];

                const f2 tx = tot[0], ty = tot[1], txx = tot[2], tyy = tot[3], txy = tot[4];
                const f2 pxy = tx * ty;
                const f2 A1  = ffma2(pxy, two, c1v);
                const f2 s2  = ffma2(tx, tx, ty * ty);
                const f2 B1  = s2 + c1v;
                const f2 mxy = ffma2(k49, txy, -pxy);
                const f2 A2  = ffma2(covn2v, mxy, c2v);
                const f2 vs  = ffma2(k49, txx + tyy, -s2);
                const f2 B2  = ffma2(covnv, vs, c2v);
                const f2 num = A1 * A2;
                const f2 den = B1 * B2;
                f2 r;
                r.x = __builtin_amdgcn_rcpf(den.x);
                r.y = __builtin_amdgcn_rcpf(den.y);
                acc2 = ffma2(num, r, acc2);

                const int sn = (p + 6) % 7;    // retire slot p, insert new in slot sn
                #pragma unroll
                for (int q = 0; q < 5; ++q) { tot[q] -= ring[q][p]; ring[q][sn] = h[q]; }
            }
        }
    }

    float acc = acc2.x + acc2.y;
    #pragma unroll
    for (int off = 32; off; off >>= 1)
        acc += __shfl_down(acc, off, 64);
    __shared__ float sm[3];
    if (lane == 0) sm[w] = acc;
    __syncthreads();
    if (t == 0) {
        const float s = sm[0] + sm[1] + sm[2];
        const int blk = blockIdx.y * NCHUNK + blockIdx.x;
        const int g   = blk & (GROUPS - 1);
        float* slots = ws + SLOT0;
        // Hierarchical completion: 64 parallel group counters (32 RMWs each),
        // then a 64-RMW root. R8's single-address counter serialized 2048 RMWs
        // (~62 us). s_waitcnt (wave-local drain) orders add -> count; no
        // buffer_inv is emitted (unlike __threadfence, which wiped L1 in R5).
        atomicAdd(&slots[g * STRIDE], s);      // 64 independent lines
        __builtin_amdgcn_s_waitcnt(0);         // slot add at L2 before counting
        unsigned* cnt1 = (unsigned*)(ws + CNT0);
        const unsigned d1 = atomicAdd(&cnt1[g * STRIDE], 1u);
        if (d1 == PER_GROUP - 1) {             // group complete (32 blocks)
            __builtin_amdgcn_s_waitcnt(0);
            const unsigned d2 = atomicAdd((unsigned*)(ws + ROOTC), 1u);
            if (d2 == GROUPS - 1) {            // all groups complete: finalize
                float totsum = 0.0f;
                #pragma unroll
                for (int i = 0; i < GROUPS; ++i)
                    totsum += atomicAdd(&slots[i * STRIDE], 0.0f);   // L2-coherent reads
                out[0] = 1.0f - totsum * (1.0f / (32.0f * 634.0f * 362.0f));
            }
        }
    }
}

extern "C" void kernel_launch(void* const* d_in, const int* in_sizes, int n_in,
                              void* d_out, int out_size, void* d_ws, size_t ws_size,
                              hipStream_t stream) {
    const float* X = (const float*)d_in[0];   // 'output'
    const float* Y = (const float*)d_in[1];   // 'target'
    float* ws = (float*)d_ws;

    k_max<<<dim3(2048), dim3(256), 0, stream>>>(Y, ws);
    k_ssim<<<dim3(NCHUNK, B_), dim3(192), 0, stream>>>(X, Y, ws, (float*)d_out);
}